// Round 3
// baseline (896.205 us; speedup 1.0000x reference)
//
#include <hip/hip_runtime.h>
#include <stdint.h>

typedef unsigned short u16;
typedef unsigned int u32;

#define NGRAPH 128

__device__ __forceinline__ float b2f(u16 u) {
    union { u32 i; float f; } c; c.i = ((u32)u) << 16; return c.f;
}
__device__ __forceinline__ u16 f2b(float f) {
    union { float f; u32 i; } c; c.f = f;
    u32 r = c.i + 0x7fffu + ((c.i >> 16) & 1u);
    return (u16)(r >> 16);
}

// ---- sentinel: fill d_out (as u16 pattern) ----
__global__ void k_sentinel(u16* __restrict__ out, int n, u16 pat) {
    int i = blockIdx.x * 256 + threadIdx.x;
    if (i < n) out[i] = pat;
}

// ---- dtype detection: EVEN u16 halves are random mantissa bits iff fp32 ----
__global__ void k_detect(const u16* __restrict__ x, int* __restrict__ flag) {
    __shared__ int cnt;
    if (threadIdx.x == 0) cnt = 0;
    __syncthreads();
    int weird = 0;
    for (int i = threadIdx.x; i < 4096; i += 256) {
        u16 u = x[2 * i];              // fp32: low mantissa half (random); bf16: element 2i (normal)
        int e = (u >> 7) & 0xff;
        if (e != 0 && (e < 100 || e > 140)) weird++;
    }
    atomicAdd(&cnt, weird);
    __syncthreads();
    if (threadIdx.x == 0) *flag = (cnt > 1024) ? 1 : 0;   // 1 = fp32 inputs
}

// ---- generic convert (fp32->bf16 or passthrough) ----
__global__ __launch_bounds__(256) void k_cvt(const void* __restrict__ src, u16* __restrict__ dst,
                                             int n, const int* __restrict__ flag) {
    int f = *flag;
    int i = blockIdx.x * 256 + threadIdx.x;
    if (i < n) dst[i] = f ? f2b(((const float*)src)[i]) : ((const u16*)src)[i];
}

__global__ __launch_bounds__(256) void k_cvt_small(
    const void* p0, const void* p1, const void* p2, const void* p3, const void* p4,
    const void* p5, const void* p6, const void* p7, const void* p8, const void* p9,
    const void* p10, const void* p11, const void* p12, const void* p13, const void* p14,
    const void* p15, const void* p16, const void* p17,
    u16* __restrict__ dst, const int* __restrict__ flag) {
    const void* ps[18] = {p0,p1,p2,p3,p4,p5,p6,p7,p8,p9,p10,p11,p12,p13,p14,p15,p16,p17};
    int f = *flag;
    int vec = blockIdx.x;          // 18 blocks
    int j = threadIdx.x;           // 256
    const void* s = ps[vec];
    dst[vec * 256 + j] = f ? f2b(((const float*)s)[j]) : ((const u16*)s)[j];
}

// ---- zero init ----
__global__ void k_zero(int* __restrict__ deg, float* __restrict__ pool, int nd, int np) {
    int i = blockIdx.x * blockDim.x + threadIdx.x;
    if (i < nd) deg[i] = 0;
    if (i < np) pool[i] = 0.0f;
}

__global__ void k_root(const int* __restrict__ batch, int* __restrict__ root, int N, int B) {
    int b = threadIdx.x;
    if (b > B) return;
    int lo = 0, hi = N;
    while (lo < hi) { int mid = (lo + hi) >> 1; if (batch[mid] < b) lo = mid + 1; else hi = mid; }
    root[b] = lo;
}

__global__ __launch_bounds__(256) void k_hist(const int* __restrict__ ei, int* __restrict__ deg, int E) {
    int e = blockIdx.x * 256 + threadIdx.x;
    if (e < E) atomicAdd(&deg[ei[E + e]], 1);
}

__global__ __launch_bounds__(256) void k_scan1(const int* __restrict__ in, int* __restrict__ out,
                                               int* __restrict__ bsums, int total) {
    __shared__ int lds[256];
    int tid = threadIdx.x;
    int base = blockIdx.x * 2048 + tid * 8;
    int v[8]; int ts = 0;
#pragma unroll
    for (int r = 0; r < 8; r++) { int i = base + r; int x = (i < total) ? in[i] : 0; v[r] = x; ts += x; }
    lds[tid] = ts;
    __syncthreads();
    for (int off = 1; off < 256; off <<= 1) {
        int t = (tid >= off) ? lds[tid - off] : 0;
        __syncthreads();
        lds[tid] += t;
        __syncthreads();
    }
    int run = lds[tid] - ts;
#pragma unroll
    for (int r = 0; r < 8; r++) { int i = base + r; if (i < total) out[i] = run; run += v[r]; }
    if (tid == 255) bsums[blockIdx.x] = lds[255];
}

__global__ void k_scan2(int* __restrict__ bsums, int nb) {
    if (threadIdx.x == 0 && blockIdx.x == 0) {
        int run = 0;
        for (int i = 0; i < nb; i++) { int t = bsums[i]; bsums[i] = run; run += t; }
    }
}

__global__ __launch_bounds__(256) void k_scan3(const int* __restrict__ pscan, const int* __restrict__ bsums,
                                               int* __restrict__ ptr, int* __restrict__ cursor,
                                               int total, int N) {
    int i = blockIdx.x * 256 + threadIdx.x;
    if (i >= total) return;
    int val = pscan[i] + bsums[i >> 11];
    ptr[i] = val;
    if (i < N) cursor[i] = val;
}

__global__ __launch_bounds__(256) void k_fill(const int* __restrict__ ei, int* __restrict__ cursor,
                                              int* __restrict__ csr, int E) {
    int e = blockIdx.x * 256 + threadIdx.x;
    if (e < E) {
        int src = ei[e];
        int pos = atomicAdd(&cursor[ei[E + e]], 1);
        csr[pos] = src;
    }
}

// ---- simple tiled GEMM: C[M,256](bf16) = A[M,256](bf16) @ W[256,256](bf16, [k][n] layout)
// optional epilogue += r2[batch[row]][col]. Block: 256 thr = 4 waves; tile 16 rows x 256 cols.
// wave w owns rows m0+4w..m0+4w+3; lane l owns cols 4l..4l+3.
__global__ __launch_bounds__(256) void k_gemm_simple(
    const u16* __restrict__ A, const u16* __restrict__ W, u16* __restrict__ C, int M,
    const float* __restrict__ r2, const int* __restrict__ batch) {
    __shared__ u16 Ws[64 * 256];
    __shared__ float As[16 * 64];
    int tid = threadIdx.x, lane = tid & 63, wave = tid >> 6;
    int m0 = blockIdx.x * 16;
    float acc[4][4] = {};

    for (int k0 = 0; k0 < 256; k0 += 64) {
        // stage W[k0:k0+64][:] : contiguous 16384 u16
        {
            const uint2* src = (const uint2*)(W + k0 * 256);
            uint2* dst = (uint2*)Ws;
            for (int i = tid; i < 4096; i += 256) dst[i] = src[i];
        }
        // stage A rows m0..m0+15, k in [k0,k0+64), converted to fp32
        {
            int r = tid >> 4;
            int kk = (tid & 15) * 4;
            int gr = m0 + r; if (gr > M - 1) gr = M - 1;
            ushort4 av = *(const ushort4*)(A + (size_t)gr * 256 + k0 + kk);
            As[r * 64 + kk + 0] = b2f(av.x);
            As[r * 64 + kk + 1] = b2f(av.y);
            As[r * 64 + kk + 2] = b2f(av.z);
            As[r * 64 + kk + 3] = b2f(av.w);
        }
        __syncthreads();
        int rb = wave * 4 * 64;
        for (int kk = 0; kk < 64; ++kk) {
            float a0 = As[rb + 0 * 64 + kk];
            float a1 = As[rb + 1 * 64 + kk];
            float a2 = As[rb + 2 * 64 + kk];
            float a3 = As[rb + 3 * 64 + kk];
            ushort4 wv = *(const ushort4*)(Ws + kk * 256 + lane * 4);
            float w0 = b2f(wv.x), w1 = b2f(wv.y), w2 = b2f(wv.z), w3 = b2f(wv.w);
            acc[0][0] += a0 * w0; acc[0][1] += a0 * w1; acc[0][2] += a0 * w2; acc[0][3] += a0 * w3;
            acc[1][0] += a1 * w0; acc[1][1] += a1 * w1; acc[1][2] += a1 * w2; acc[1][3] += a1 * w3;
            acc[2][0] += a2 * w0; acc[2][1] += a2 * w1; acc[2][2] += a2 * w2; acc[2][3] += a2 * w3;
            acc[3][0] += a3 * w0; acc[3][1] += a3 * w1; acc[3][2] += a3 * w2; acc[3][3] += a3 * w3;
        }
        __syncthreads();
    }
    int rbase = m0 + wave * 4;
#pragma unroll
    for (int r = 0; r < 4; ++r) {
        int row = rbase + r;
        if (row >= M) continue;
        const float* r2p = r2 ? (r2 + (size_t)batch[row] * 256) : nullptr;
#pragma unroll
        for (int j = 0; j < 4; ++j) {
            int col = lane * 4 + j;
            float v = acc[r][j];
            if (r2p) v += r2p[col];
            C[(size_t)row * 256 + col] = f2b(v);
        }
    }
}

// ---- attention logits ----
__global__ __launch_bounds__(256) void k_al(const u16* __restrict__ h, const u16* __restrict__ a_s,
                                            const u16* __restrict__ a_d,
                                            float* __restrict__ al_s, float* __restrict__ al_d, int N) {
    int node = blockIdx.x * 4 + (threadIdx.x >> 6);
    if (node >= N) return;
    int lane = threadIdx.x & 63;
    int c0 = lane * 4;
    int head = lane >> 4;
    int ci = c0 & 63;
    ushort4 hv = *(const ushort4*)(h + (size_t)node * 256 + c0);
    float h0 = b2f(hv.x), h1 = b2f(hv.y), h2 = b2f(hv.z), h3 = b2f(hv.w);
    ushort4 sv = *(const ushort4*)(a_s + head * 64 + ci);
    ushort4 dv = *(const ushort4*)(a_d + head * 64 + ci);
    float ps = h0 * b2f(sv.x) + h1 * b2f(sv.y) + h2 * b2f(sv.z) + h3 * b2f(sv.w);
    float pd = h0 * b2f(dv.x) + h1 * b2f(dv.y) + h2 * b2f(dv.z) + h3 * b2f(dv.w);
#pragma unroll
    for (int off = 1; off < 16; off <<= 1) { ps += __shfl_xor(ps, off); pd += __shfl_xor(pd, off); }
    if ((lane & 15) == 0) { al_s[node * 4 + head] = ps; al_d[node * 4 + head] = pd; }
}

// ---- fused GAT aggregation + bias + BN + LN + ReLU (+ pool) ----
__global__ __launch_bounds__(256) void k_agg(
    const u16* __restrict__ h, const float* __restrict__ als, const float* __restrict__ ald_,
    const int* __restrict__ ptr, const int* __restrict__ csr,
    const u16* __restrict__ bias, const u16* __restrict__ bng, const u16* __restrict__ bnb,
    const u16* __restrict__ bnm, const u16* __restrict__ bnv,
    const u16* __restrict__ lng, const u16* __restrict__ lnb,
    u16* __restrict__ xout, float* __restrict__ pool, const int* __restrict__ batch, int N) {
    int node = blockIdx.x * 4 + (threadIdx.x >> 6);
    if (node >= N) return;
    int lane = threadIdx.x & 63;
    int c0 = lane * 4;
    int head = lane >> 4;
    float ad = ald_[node * 4 + head];
    float e = als[node * 4 + head] + ad; e = (e > 0.f) ? e : 0.2f * e;   // self loop
    float m = e, s = 1.0f;
    ushort4 hv = *(const ushort4*)(h + (size_t)node * 256 + c0);
    float a0 = b2f(hv.x), a1 = b2f(hv.y), a2 = b2f(hv.z), a3 = b2f(hv.w);
    int beg = ptr[node], end = ptr[node + 1];
    for (int i = beg; i < end; ++i) {
        int src = csr[i];
        float e2 = als[src * 4 + head] + ad; e2 = (e2 > 0.f) ? e2 : 0.2f * e2;
        float mn = fmaxf(m, e2);
        float sc = __expf(m - mn);
        float p  = __expf(e2 - mn);
        ushort4 hw = *(const ushort4*)(h + (size_t)src * 256 + c0);
        s = s * sc + p;
        a0 = a0 * sc + p * b2f(hw.x);
        a1 = a1 * sc + p * b2f(hw.y);
        a2 = a2 * sc + p * b2f(hw.z);
        a3 = a3 * sc + p * b2f(hw.w);
        m = mn;
    }
    float inv = 1.0f / (s + 1e-16f);
    float v0 = a0 * inv + b2f(bias[c0 + 0]);
    float v1 = a1 * inv + b2f(bias[c0 + 1]);
    float v2 = a2 * inv + b2f(bias[c0 + 2]);
    float v3 = a3 * inv + b2f(bias[c0 + 3]);
    v0 = (v0 - b2f(bnm[c0 + 0])) * (b2f(bng[c0 + 0]) * rsqrtf(b2f(bnv[c0 + 0]) + 1e-5f)) + b2f(bnb[c0 + 0]);
    v1 = (v1 - b2f(bnm[c0 + 1])) * (b2f(bng[c0 + 1]) * rsqrtf(b2f(bnv[c0 + 1]) + 1e-5f)) + b2f(bnb[c0 + 1]);
    v2 = (v2 - b2f(bnm[c0 + 2])) * (b2f(bng[c0 + 2]) * rsqrtf(b2f(bnv[c0 + 2]) + 1e-5f)) + b2f(bnb[c0 + 2]);
    v3 = (v3 - b2f(bnm[c0 + 3])) * (b2f(bng[c0 + 3]) * rsqrtf(b2f(bnv[c0 + 3]) + 1e-5f)) + b2f(bnb[c0 + 3]);
    float sum = v0 + v1 + v2 + v3;
#pragma unroll
    for (int off = 1; off < 64; off <<= 1) sum += __shfl_xor(sum, off);
    float mu = sum * 0.00390625f;
    float d0 = v0 - mu, d1 = v1 - mu, d2 = v2 - mu, d3 = v3 - mu;
    float q = d0 * d0 + d1 * d1 + d2 * d2 + d3 * d3;
#pragma unroll
    for (int off = 1; off < 64; off <<= 1) q += __shfl_xor(q, off);
    float rstd = rsqrtf(q * 0.00390625f + 1e-5f);
    float y0 = fmaxf(d0 * rstd * b2f(lng[c0 + 0]) + b2f(lnb[c0 + 0]), 0.f);
    float y1 = fmaxf(d1 * rstd * b2f(lng[c0 + 1]) + b2f(lnb[c0 + 1]), 0.f);
    float y2 = fmaxf(d2 * rstd * b2f(lng[c0 + 2]) + b2f(lnb[c0 + 2]), 0.f);
    float y3 = fmaxf(d3 * rstd * b2f(lng[c0 + 3]) + b2f(lnb[c0 + 3]), 0.f);
    if (xout) {
        u16* o = xout + (size_t)node * 256 + c0;
        o[0] = f2b(y0); o[1] = f2b(y1); o[2] = f2b(y2); o[3] = f2b(y3);
    }
    if (pool) {
        int g = batch[node];
        float* pp = pool + (size_t)g * 256 + c0;
        atomicAdd(pp + 0, y0); atomicAdd(pp + 1, y1); atomicAdd(pp + 2, y2); atomicAdd(pp + 3, y3);
    }
}

// ---- r2[b] = x[root_b] @ W2[256:512,:] ----
__global__ __launch_bounds__(256) void k_r2(const u16* __restrict__ xc, const u16* __restrict__ w2,
                                            const int* __restrict__ root, float* __restrict__ r2, int N) {
    __shared__ float xs[256];
    int b = blockIdx.x, c = threadIdx.x;
    int rt = root[b]; if (rt >= N) rt = N - 1; if (rt < 0) rt = 0;
    xs[c] = b2f(xc[(size_t)rt * 256 + c]);
    __syncthreads();
    float acc = 0.f;
    for (int k = 0; k < 256; k++) acc += xs[k] * b2f(w2[(size_t)(256 + k) * 256 + c]);
    r2[b * 256 + c] = acc;
}

// ---- final: out[b] = [pool[b]/cnt, x2[root_b]] ----
__global__ __launch_bounds__(256) void k_final(const float* __restrict__ pool, const u16* __restrict__ x2,
                                               const int* __restrict__ root, void* __restrict__ out,
                                               const int* __restrict__ flag) {
    int b = blockIdx.x, c = threadIdx.x;
    int r0 = root[b], r1 = root[b + 1];
    int cnt = r1 - r0;
    float inv = 1.0f / (float)(cnt > 1 ? cnt : 1);
    float v0 = pool[b * 256 + c] * inv;
    float v1 = (cnt > 0) ? b2f(x2[(size_t)r0 * 256 + c]) : 0.0f;
    if (*flag) {
        float* o = (float*)out;
        o[b * 512 + c] = v0;
        o[b * 512 + 256 + c] = v1;
    } else {
        u16* o = (u16*)out;
        o[b * 512 + c] = f2b(v0);
        o[b * 512 + 256 + c] = f2b(v1);
    }
}

extern "C" void kernel_launch(void* const* d_in, const int* in_sizes, int n_in,
                              void* d_out, int out_size, void* d_ws, size_t ws_size,
                              hipStream_t stream) {
    u16* outp = (u16*)d_out;
    int ogrid = (out_size + 255) / 256;

    if (n_in != 23) {   // harness-contract mismatch sentinel: 2000.0
        k_sentinel<<<ogrid, 256, 0, stream>>>(outp, out_size, (u16)0x44FA);
        return;
    }

    const void* x_raw = d_in[0];
    const int* ei = (const int*)d_in[1];
    const int* batch = (const int*)d_in[2];
    const int NX = in_sizes[0];
    const int E = in_sizes[1] / 2;
    const int N = in_sizes[2];
    const int NW1 = in_sizes[3];
    const int NW2 = in_sizes[13];
    const int B = NGRAPH;

    char* p = (char*)d_ws;
    auto carve = [&](size_t bytes) -> void* {
        void* r = (void*)p; p += (bytes + 255) & ~(size_t)255; return r;
    };
    u16* xc    = (u16*)carve((size_t)NX * 2);
    u16* w1c   = (u16*)carve((size_t)NW1 * 2);
    u16* w2c   = (u16*)carve((size_t)NW2 * 2);
    u16* sc    = (u16*)carve((size_t)18 * 256 * 2);
    u16* hbuf  = (u16*)carve((size_t)N * 256 * 2);
    u16* x2    = (u16*)carve((size_t)N * 256 * 2);
    float* als = (float*)carve((size_t)N * 4 * 4);
    float* ald = (float*)carve((size_t)N * 4 * 4);
    int* deg    = (int*)carve((size_t)(N + 1) * 4);
    int* pscan  = (int*)carve((size_t)(N + 1) * 4);
    int* ptr    = (int*)carve((size_t)(N + 1) * 4);
    int* cursor = (int*)carve((size_t)N * 4);
    int* csr    = (int*)carve((size_t)E * 4);
    int* bsums  = (int*)carve(1024);
    int* root   = (int*)carve((size_t)(B + 1) * 4);
    float* r2   = (float*)carve((size_t)B * 256 * 4);
    float* pool = (float*)carve((size_t)B * 256 * 4);
    int* flag   = (int*)carve(256);

    size_t needed = (size_t)(p - (char*)d_ws);
    if (needed > ws_size) {   // workspace-too-small sentinel: 1000.0
        k_sentinel<<<ogrid, 256, 0, stream>>>(outp, out_size, (u16)0x447A);
        return;
    }

    // sentinel 100.0 — overwritten by k_final if the pipeline completes
    k_sentinel<<<ogrid, 256, 0, stream>>>(outp, out_size, (u16)0x42C8);

    k_detect<<<1, 256, 0, stream>>>((const u16*)x_raw, flag);

    int zmax = (N + 1) > (B * 256) ? (N + 1) : (B * 256);
    k_zero<<<(zmax + 255) / 256, 256, 0, stream>>>(deg, pool, N + 1, B * 256);

    k_cvt<<<(NX + 255) / 256, 256, 0, stream>>>(x_raw, xc, NX, flag);
    k_cvt<<<(NW1 + 255) / 256, 256, 0, stream>>>(d_in[3], w1c, NW1, flag);
    k_cvt<<<(NW2 + 255) / 256, 256, 0, stream>>>(d_in[13], w2c, NW2, flag);
    k_cvt_small<<<18, 256, 0, stream>>>(
        d_in[4], d_in[5], d_in[6], d_in[7], d_in[8], d_in[9], d_in[10], d_in[11], d_in[12],
        d_in[14], d_in[15], d_in[16], d_in[17], d_in[18], d_in[19], d_in[20], d_in[21], d_in[22],
        sc, flag);

    k_root<<<1, 256, 0, stream>>>(batch, root, N, B);

    k_hist<<<(E + 255) / 256, 256, 0, stream>>>(ei, deg, E);
    int nb1 = (N + 1 + 2047) / 2048;
    k_scan1<<<nb1, 256, 0, stream>>>(deg, pscan, bsums, N + 1);
    k_scan2<<<1, 64, 0, stream>>>(bsums, nb1);
    k_scan3<<<(N + 1 + 255) / 256, 256, 0, stream>>>(pscan, bsums, ptr, cursor, N + 1, N);
    k_fill<<<(E + 255) / 256, 256, 0, stream>>>(ei, cursor, csr, E);

    int gblocks = (N + 15) / 16;
    // layer 1
    k_gemm_simple<<<gblocks, 256, 0, stream>>>(xc, w1c, hbuf, N, nullptr, nullptr);
    k_al<<<(N + 3) / 4, 256, 0, stream>>>(hbuf, sc + 0 * 256, sc + 1 * 256, als, ald, N);
    k_agg<<<(N + 3) / 4, 256, 0, stream>>>(hbuf, als, ald, ptr, csr,
        sc + 2 * 256, sc + 3 * 256, sc + 4 * 256, sc + 5 * 256, sc + 6 * 256, sc + 7 * 256, sc + 8 * 256,
        x2, nullptr, batch, N);
    // layer 2
    k_r2<<<B, 256, 0, stream>>>(xc, w2c, root, r2, N);
    k_gemm_simple<<<gblocks, 256, 0, stream>>>(x2, w2c, hbuf, N, r2, batch);
    k_al<<<(N + 3) / 4, 256, 0, stream>>>(hbuf, sc + 9 * 256, sc + 10 * 256, als, ald, N);
    k_agg<<<(N + 3) / 4, 256, 0, stream>>>(hbuf, als, ald, ptr, csr,
        sc + 11 * 256, sc + 12 * 256, sc + 13 * 256, sc + 14 * 256, sc + 15 * 256, sc + 16 * 256, sc + 17 * 256,
        nullptr, pool, batch, N);

    k_final<<<B, 256, 0, stream>>>(pool, x2, root, d_out, flag);
    (void)ws_size;
}

// Round 4
// 795.367 us; speedup vs baseline: 1.1268x; 1.1268x over previous
//
#include <hip/hip_runtime.h>
#include <stdint.h>

typedef unsigned short u16;
typedef unsigned int u32;
typedef __bf16 bf16x8 __attribute__((ext_vector_type(8)));
typedef float f32x4 __attribute__((ext_vector_type(4)));

#define NGRAPH 128

__device__ __forceinline__ float b2f(u16 u) {
    union { u32 i; float f; } c; c.i = ((u32)u) << 16; return c.f;
}
__device__ __forceinline__ u16 f2b(float f) {
    union { float f; u32 i; } c; c.f = f;
    u32 r = c.i + 0x7fffu + ((c.i >> 16) & 1u);
    return (u16)(r >> 16);
}

// ---- sentinel ----
__global__ void k_sentinel(u16* __restrict__ out, int n, u16 pat) {
    int i = blockIdx.x * 256 + threadIdx.x;
    if (i < n) out[i] = pat;
}

// ---- dtype detection ----
__global__ void k_detect(const u16* __restrict__ x, int* __restrict__ flag) {
    __shared__ int cnt;
    if (threadIdx.x == 0) cnt = 0;
    __syncthreads();
    int weird = 0;
    for (int i = threadIdx.x; i < 4096; i += 256) {
        u16 u = x[2 * i];
        int e = (u >> 7) & 0xff;
        if (e != 0 && (e < 100 || e > 140)) weird++;
    }
    atomicAdd(&cnt, weird);
    __syncthreads();
    if (threadIdx.x == 0) *flag = (cnt > 1024) ? 1 : 0;   // 1 = fp32 inputs
}

// ---- convert ----
__global__ __launch_bounds__(256) void k_cvt(const void* __restrict__ src, u16* __restrict__ dst,
                                             int n, const int* __restrict__ flag) {
    int f = *flag;
    int i = blockIdx.x * 256 + threadIdx.x;
    if (i < n) dst[i] = f ? f2b(((const float*)src)[i]) : ((const u16*)src)[i];
}

__global__ __launch_bounds__(256) void k_cvt_small(
    const void* p0, const void* p1, const void* p2, const void* p3, const void* p4,
    const void* p5, const void* p6, const void* p7, const void* p8, const void* p9,
    const void* p10, const void* p11, const void* p12, const void* p13, const void* p14,
    const void* p15, const void* p16, const void* p17,
    u16* __restrict__ dst, const int* __restrict__ flag) {
    const void* ps[18] = {p0,p1,p2,p3,p4,p5,p6,p7,p8,p9,p10,p11,p12,p13,p14,p15,p16,p17};
    int f = *flag;
    int vec = blockIdx.x;
    int j = threadIdx.x;
    const void* s = ps[vec];
    dst[vec * 256 + j] = f ? f2b(((const float*)s)[j]) : ((const u16*)s)[j];
}

// ---- zero init ----
__global__ void k_zero(int* __restrict__ deg, float* __restrict__ pool, int nd, int np) {
    int i = blockIdx.x * blockDim.x + threadIdx.x;
    if (i < nd) deg[i] = 0;
    if (i < np) pool[i] = 0.0f;
}

// ---- transpose 256x256 ----
__global__ void k_transpose(const u16* __restrict__ w, u16* __restrict__ wt) {
    int idx = blockIdx.x * 256 + threadIdx.x;
    int n = idx >> 8, k = idx & 255;
    wt[n * 256 + k] = w[k * 256 + n];
}

__global__ void k_root(const int* __restrict__ batch, int* __restrict__ root, int N, int B) {
    int b = threadIdx.x;
    if (b > B) return;
    int lo = 0, hi = N;
    while (lo < hi) { int mid = (lo + hi) >> 1; if (batch[mid] < b) lo = mid + 1; else hi = mid; }
    root[b] = lo;
}

__global__ __launch_bounds__(256) void k_hist(const int* __restrict__ ei, int* __restrict__ deg, int E) {
    int e = blockIdx.x * 256 + threadIdx.x;
    if (e < E) atomicAdd(&deg[ei[E + e]], 1);
}

__global__ __launch_bounds__(256) void k_scan1(const int* __restrict__ in, int* __restrict__ out,
                                               int* __restrict__ bsums, int total) {
    __shared__ int lds[256];
    int tid = threadIdx.x;
    int base = blockIdx.x * 2048 + tid * 8;
    int v[8]; int ts = 0;
#pragma unroll
    for (int r = 0; r < 8; r++) { int i = base + r; int x = (i < total) ? in[i] : 0; v[r] = x; ts += x; }
    lds[tid] = ts;
    __syncthreads();
    for (int off = 1; off < 256; off <<= 1) {
        int t = (tid >= off) ? lds[tid - off] : 0;
        __syncthreads();
        lds[tid] += t;
        __syncthreads();
    }
    int run = lds[tid] - ts;
#pragma unroll
    for (int r = 0; r < 8; r++) { int i = base + r; if (i < total) out[i] = run; run += v[r]; }
    if (tid == 255) bsums[blockIdx.x] = lds[255];
}

__global__ void k_scan2(int* __restrict__ bsums, int nb) {
    if (threadIdx.x == 0 && blockIdx.x == 0) {
        int run = 0;
        for (int i = 0; i < nb; i++) { int t = bsums[i]; bsums[i] = run; run += t; }
    }
}

__global__ __launch_bounds__(256) void k_scan3(const int* __restrict__ pscan, const int* __restrict__ bsums,
                                               int* __restrict__ ptr, int* __restrict__ cursor,
                                               int total, int N) {
    int i = blockIdx.x * 256 + threadIdx.x;
    if (i >= total) return;
    int val = pscan[i] + bsums[i >> 11];
    ptr[i] = val;
    if (i < N) cursor[i] = val;
}

__global__ __launch_bounds__(256) void k_fill(const int* __restrict__ ei, int* __restrict__ cursor,
                                              int* __restrict__ csr, int E) {
    int e = blockIdx.x * 256 + threadIdx.x;
    if (e < E) {
        int src = ei[e];
        int pos = atomicAdd(&cursor[ei[E + e]], 1);
        csr[pos] = src;
    }
}

// ---- MFMA GEMM: C[M,256](bf16) = A[M,256] @ Bt^T, Bt = [256 n-rows][256 k]
// optional epilogue += r2[batch[row]][col]. 128x128 tile, 4 waves, 16x16x32 bf16.
__global__ __launch_bounds__(256) void k_gemm(const u16* __restrict__ A, const u16* __restrict__ Bt,
                                              u16* __restrict__ C, int M,
                                              const float* __restrict__ r2, const int* __restrict__ batch) {
    __shared__ __align__(16) u16 As[128 * 64];
    __shared__ __align__(16) u16 Bs[128 * 64];
    const int tid = threadIdx.x;
    const int lane = tid & 63;
    const int wave = tid >> 6;
    const int bm = blockIdx.x >> 1;
    const int bn = blockIdx.x & 1;
    const int m0 = bm * 128, n0 = bn * 128;
    const int wm = wave >> 1, wn = wave & 1;
    const int lm = lane & 15, lq = lane >> 4;
    f32x4 acc[4][4] = {};

    for (int k0 = 0; k0 < 256; k0 += 64) {
        uint4 ra[4], rb[4];
#pragma unroll
        for (int it = 0; it < 4; ++it) {
            int t = tid + 256 * it;
            int m = t >> 3;
            int kc = (t & 7) ^ (m & 7);        // XOR swizzle
            int gm = m0 + m; if (gm > M - 1) gm = M - 1;
            ra[it] = *(const uint4*)(A + (size_t)gm * 256 + k0 + kc * 8);
            rb[it] = *(const uint4*)(Bt + (size_t)(n0 + m) * 256 + k0 + kc * 8);
        }
        __syncthreads();
#pragma unroll
        for (int it = 0; it < 4; ++it) {
            int t = tid + 256 * it;
            *(uint4*)(As + t * 8) = ra[it];
            *(uint4*)(Bs + t * 8) = rb[it];
        }
        __syncthreads();
#pragma unroll
        for (int ks = 0; ks < 2; ++ks) {
            int kq = ks * 4 + lq;
            bf16x8 af[4], bfr[4];
#pragma unroll
            for (int i = 0; i < 4; i++) {
                int m = wm * 64 + i * 16 + lm;
                af[i] = *(const bf16x8*)(As + (m * 8 + (kq ^ (m & 7))) * 8);
                int n = wn * 64 + i * 16 + lm;
                bfr[i] = *(const bf16x8*)(Bs + (n * 8 + (kq ^ (n & 7))) * 8);
            }
#pragma unroll
            for (int i = 0; i < 4; i++)
#pragma unroll
                for (int j = 0; j < 4; j++)
                    acc[i][j] = __builtin_amdgcn_mfma_f32_16x16x32_bf16(af[i], bfr[j], acc[i][j], 0, 0, 0);
        }
    }
#pragma unroll
    for (int i = 0; i < 4; i++) {
#pragma unroll
        for (int r = 0; r < 4; r++) {
            int row = m0 + wm * 64 + i * 16 + lq * 4 + r;
            if (row >= M) continue;
            const float* r2row = r2 ? (r2 + (size_t)batch[row] * 256) : nullptr;
#pragma unroll
            for (int j = 0; j < 4; j++) {
                int col = n0 + wn * 64 + j * 16 + lm;
                float v = acc[i][j][r];
                if (r2row) v += r2row[col];
                C[(size_t)row * 256 + col] = f2b(v);
            }
        }
    }
}

// ---- attention logits ----
__global__ __launch_bounds__(256) void k_al(const u16* __restrict__ h, const u16* __restrict__ a_s,
                                            const u16* __restrict__ a_d,
                                            float* __restrict__ al_s, float* __restrict__ al_d, int N) {
    int node = blockIdx.x * 4 + (threadIdx.x >> 6);
    if (node >= N) return;
    int lane = threadIdx.x & 63;
    int c0 = lane * 4;
    int head = lane >> 4;
    int ci = c0 & 63;
    ushort4 hv = *(const ushort4*)(h + (size_t)node * 256 + c0);
    float h0 = b2f(hv.x), h1 = b2f(hv.y), h2 = b2f(hv.z), h3 = b2f(hv.w);
    ushort4 sv = *(const ushort4*)(a_s + head * 64 + ci);
    ushort4 dv = *(const ushort4*)(a_d + head * 64 + ci);
    float ps = h0 * b2f(sv.x) + h1 * b2f(sv.y) + h2 * b2f(sv.z) + h3 * b2f(sv.w);
    float pd = h0 * b2f(dv.x) + h1 * b2f(dv.y) + h2 * b2f(dv.z) + h3 * b2f(dv.w);
#pragma unroll
    for (int off = 1; off < 16; off <<= 1) { ps += __shfl_xor(ps, off); pd += __shfl_xor(pd, off); }
    if ((lane & 15) == 0) { al_s[node * 4 + head] = ps; al_d[node * 4 + head] = pd; }
}

// ---- pass A: per-edge softmax weights (edge-parallel within wave) ----
// lane = e_local*4 + head; 16 edges x 4 heads per chunk.
__global__ __launch_bounds__(256) void k_attw(
    const float* __restrict__ als, const float* __restrict__ ald_,
    const int* __restrict__ ptr, const int* __restrict__ csr,
    float* __restrict__ aw, float* __restrict__ selfp, float* __restrict__ invs, int N) {
    int node = blockIdx.x * 4 + (threadIdx.x >> 6);
    if (node >= N) return;
    int lane = threadIdx.x & 63;
    int hd = lane & 3;
    int el = lane >> 2;
    int beg = ptr[node], end = ptr[node + 1];
    float ad = ald_[node * 4 + hd];
    float es = als[node * 4 + hd] + ad; es = (es > 0.f) ? es : 0.2f * es;   // self loop
    float m = es;
    for (int i0 = beg; i0 < end; i0 += 16) {
        int i = i0 + el;
        if (i < end) {
            int src = csr[i];
            float e2 = als[src * 4 + hd] + ad; e2 = (e2 > 0.f) ? e2 : 0.2f * e2;
            m = fmaxf(m, e2);
        }
    }
#pragma unroll
    for (int off = 4; off < 64; off <<= 1) m = fmaxf(m, __shfl_xor(m, off));
    float s = 0.f;
    for (int i0 = beg; i0 < end; i0 += 16) {
        int i = i0 + el;
        if (i < end) {
            int src = csr[i];
            float e2 = als[src * 4 + hd] + ad; e2 = (e2 > 0.f) ? e2 : 0.2f * e2;
            float p = __expf(e2 - m);
            aw[(size_t)i * 4 + hd] = p;
            s += p;
        }
    }
#pragma unroll
    for (int off = 4; off < 64; off <<= 1) s += __shfl_xor(s, off);
    float pself = __expf(es - m);
    s += pself;
    if (el == 0) {
        float inv = 1.0f / (s + 1e-16f);
        selfp[node * 4 + hd] = pself * inv;
        invs[node * 4 + hd] = inv;
    }
}

// ---- pass B: weighted gather-accumulate + bias/BN/LN/ReLU (+pool), 4-deep unrolled ----
__global__ __launch_bounds__(256) void k_agg2(
    const u16* __restrict__ h, const float* __restrict__ aw,
    const float* __restrict__ selfp, const float* __restrict__ invs,
    const int* __restrict__ ptr, const int* __restrict__ csr,
    const u16* __restrict__ bias, const u16* __restrict__ bng, const u16* __restrict__ bnb,
    const u16* __restrict__ bnm, const u16* __restrict__ bnv,
    const u16* __restrict__ lng, const u16* __restrict__ lnb,
    u16* __restrict__ xout, float* __restrict__ pool, const int* __restrict__ batch, int N) {
    int node = blockIdx.x * 4 + (threadIdx.x >> 6);
    if (node >= N) return;
    int lane = threadIdx.x & 63;
    int c0 = lane * 4;
    int head = lane >> 4;
    int beg = ptr[node], end = ptr[node + 1];
    float a0 = 0.f, a1 = 0.f, a2 = 0.f, a3 = 0.f;
    int i = beg;
    for (; i + 4 <= end; i += 4) {
        int s0 = csr[i], s1 = csr[i + 1], s2 = csr[i + 2], s3 = csr[i + 3];
        float p0 = aw[(size_t)i * 4 + head];
        float p1 = aw[(size_t)(i + 1) * 4 + head];
        float p2 = aw[(size_t)(i + 2) * 4 + head];
        float p3 = aw[(size_t)(i + 3) * 4 + head];
        ushort4 r0 = *(const ushort4*)(h + (size_t)s0 * 256 + c0);
        ushort4 r1 = *(const ushort4*)(h + (size_t)s1 * 256 + c0);
        ushort4 r2v = *(const ushort4*)(h + (size_t)s2 * 256 + c0);
        ushort4 r3 = *(const ushort4*)(h + (size_t)s3 * 256 + c0);
        a0 += p0 * b2f(r0.x) + p1 * b2f(r1.x) + p2 * b2f(r2v.x) + p3 * b2f(r3.x);
        a1 += p0 * b2f(r0.y) + p1 * b2f(r1.y) + p2 * b2f(r2v.y) + p3 * b2f(r3.y);
        a2 += p0 * b2f(r0.z) + p1 * b2f(r1.z) + p2 * b2f(r2v.z) + p3 * b2f(r3.z);
        a3 += p0 * b2f(r0.w) + p1 * b2f(r1.w) + p2 * b2f(r2v.w) + p3 * b2f(r3.w);
    }
    for (; i < end; ++i) {
        int s0 = csr[i];
        float p0 = aw[(size_t)i * 4 + head];
        ushort4 r0 = *(const ushort4*)(h + (size_t)s0 * 256 + c0);
        a0 += p0 * b2f(r0.x); a1 += p0 * b2f(r0.y); a2 += p0 * b2f(r0.z); a3 += p0 * b2f(r0.w);
    }
    float inv = invs[node * 4 + head];
    float sp = selfp[node * 4 + head];
    ushort4 hs = *(const ushort4*)(h + (size_t)node * 256 + c0);
    float v0 = a0 * inv + sp * b2f(hs.x) + b2f(bias[c0 + 0]);
    float v1 = a1 * inv + sp * b2f(hs.y) + b2f(bias[c0 + 1]);
    float v2 = a2 * inv + sp * b2f(hs.z) + b2f(bias[c0 + 2]);
    float v3 = a3 * inv + sp * b2f(hs.w) + b2f(bias[c0 + 3]);
    v0 = (v0 - b2f(bnm[c0 + 0])) * (b2f(bng[c0 + 0]) * rsqrtf(b2f(bnv[c0 + 0]) + 1e-5f)) + b2f(bnb[c0 + 0]);
    v1 = (v1 - b2f(bnm[c0 + 1])) * (b2f(bng[c0 + 1]) * rsqrtf(b2f(bnv[c0 + 1]) + 1e-5f)) + b2f(bnb[c0 + 1]);
    v2 = (v2 - b2f(bnm[c0 + 2])) * (b2f(bng[c0 + 2]) * rsqrtf(b2f(bnv[c0 + 2]) + 1e-5f)) + b2f(bnb[c0 + 2]);
    v3 = (v3 - b2f(bnm[c0 + 3])) * (b2f(bng[c0 + 3]) * rsqrtf(b2f(bnv[c0 + 3]) + 1e-5f)) + b2f(bnb[c0 + 3]);
    float sum = v0 + v1 + v2 + v3;
#pragma unroll
    for (int off = 1; off < 64; off <<= 1) sum += __shfl_xor(sum, off);
    float mu = sum * 0.00390625f;
    float d0 = v0 - mu, d1 = v1 - mu, d2 = v2 - mu, d3 = v3 - mu;
    float q = d0 * d0 + d1 * d1 + d2 * d2 + d3 * d3;
#pragma unroll
    for (int off = 1; off < 64; off <<= 1) q += __shfl_xor(q, off);
    float rstd = rsqrtf(q * 0.00390625f + 1e-5f);
    float y0 = fmaxf(d0 * rstd * b2f(lng[c0 + 0]) + b2f(lnb[c0 + 0]), 0.f);
    float y1 = fmaxf(d1 * rstd * b2f(lng[c0 + 1]) + b2f(lnb[c0 + 1]), 0.f);
    float y2 = fmaxf(d2 * rstd * b2f(lng[c0 + 2]) + b2f(lnb[c0 + 2]), 0.f);
    float y3 = fmaxf(d3 * rstd * b2f(lng[c0 + 3]) + b2f(lnb[c0 + 3]), 0.f);
    if (xout) {
        uint2 o;
        o.x = (u32)f2b(y0) | ((u32)f2b(y1) << 16);
        o.y = (u32)f2b(y2) | ((u32)f2b(y3) << 16);
        *(uint2*)(xout + (size_t)node * 256 + c0) = o;
    }
    if (pool) {
        int g = batch[node];
        float* pp = pool + (size_t)g * 256 + c0;
        atomicAdd(pp + 0, y0); atomicAdd(pp + 1, y1); atomicAdd(pp + 2, y2); atomicAdd(pp + 3, y3);
    }
}

// ---- r2[b] = x[root_b] @ W2[256:512,:] ----
__global__ __launch_bounds__(256) void k_r2(const u16* __restrict__ xc, const u16* __restrict__ w2,
                                            const int* __restrict__ root, float* __restrict__ r2, int N) {
    __shared__ float xs[256];
    int b = blockIdx.x, c = threadIdx.x;
    int rt = root[b]; if (rt >= N) rt = N - 1; if (rt < 0) rt = 0;
    xs[c] = b2f(xc[(size_t)rt * 256 + c]);
    __syncthreads();
    float acc = 0.f;
    for (int k = 0; k < 256; k++) acc += xs[k] * b2f(w2[(size_t)(256 + k) * 256 + c]);
    r2[b * 256 + c] = acc;
}

// ---- final ----
__global__ void k_final(const float* __restrict__ pool, const u16* __restrict__ x2,
                        const int* __restrict__ root, void* __restrict__ out,
                        const int* __restrict__ flag) {
    int b = blockIdx.x, c = threadIdx.x;
    int r0 = root[b], r1 = root[b + 1];
    int cnt = r1 - r0;
    float inv = 1.0f / (float)(cnt > 1 ? cnt : 1);
    float v0 = pool[b * 256 + c] * inv;
    float v1 = (cnt > 0) ? b2f(x2[(size_t)r0 * 256 + c]) : 0.0f;
    if (*flag) {
        float* o = (float*)out;
        o[b * 512 + c] = v0;
        o[b * 512 + 256 + c] = v1;
    } else {
        u16* o = (u16*)out;
        o[b * 512 + c] = f2b(v0);
        o[b * 512 + 256 + c] = f2b(v1);
    }
}

extern "C" void kernel_launch(void* const* d_in, const int* in_sizes, int n_in,
                              void* d_out, int out_size, void* d_ws, size_t ws_size,
                              hipStream_t stream) {
    u16* outp = (u16*)d_out;
    int ogrid = (out_size + 255) / 256;

    if (n_in != 23) {
        k_sentinel<<<ogrid, 256, 0, stream>>>(outp, out_size, (u16)0x44FA);
        return;
    }

    const void* x_raw = d_in[0];
    const int* ei = (const int*)d_in[1];
    const int* batch = (const int*)d_in[2];
    const int NX = in_sizes[0];
    const int E = in_sizes[1] / 2;
    const int N = in_sizes[2];
    const int NW1 = in_sizes[3];
    const int NW2 = in_sizes[13];
    const int B = NGRAPH;

    char* p = (char*)d_ws;
    auto carve = [&](size_t bytes) -> void* {
        void* r = (void*)p; p += (bytes + 255) & ~(size_t)255; return r;
    };
    u16* xc    = (u16*)carve((size_t)NX * 2);
    u16* w1c   = (u16*)carve((size_t)NW1 * 2);
    u16* w2c   = (u16*)carve((size_t)NW2 * 2);
    u16* sc    = (u16*)carve((size_t)18 * 256 * 2);
    u16* wt1   = (u16*)carve((size_t)65536 * 2);
    u16* wt2   = (u16*)carve((size_t)65536 * 2);
    u16* hbuf  = (u16*)carve((size_t)N * 256 * 2);
    u16* x2    = (u16*)carve((size_t)N * 256 * 2);
    float* als = (float*)carve((size_t)N * 4 * 4);
    float* ald = (float*)carve((size_t)N * 4 * 4);
    float* aw  = (float*)carve((size_t)E * 4 * 4);
    float* sfp = (float*)carve((size_t)N * 4 * 4);
    float* ivs = (float*)carve((size_t)N * 4 * 4);
    int* deg    = (int*)carve((size_t)(N + 1) * 4);
    int* pscan  = (int*)carve((size_t)(N + 1) * 4);
    int* ptr    = (int*)carve((size_t)(N + 1) * 4);
    int* cursor = (int*)carve((size_t)N * 4);
    int* csr    = (int*)carve((size_t)E * 4);
    int* bsums  = (int*)carve(1024);
    int* root   = (int*)carve((size_t)(B + 1) * 4);
    float* r2   = (float*)carve((size_t)B * 256 * 4);
    float* pool = (float*)carve((size_t)B * 256 * 4);
    int* flag   = (int*)carve(256);

    size_t needed = (size_t)(p - (char*)d_ws);
    if (needed > ws_size) {
        k_sentinel<<<ogrid, 256, 0, stream>>>(outp, out_size, (u16)0x447A);
        return;
    }

    k_detect<<<1, 256, 0, stream>>>((const u16*)x_raw, flag);

    int zmax = (N + 1) > (B * 256) ? (N + 1) : (B * 256);
    k_zero<<<(zmax + 255) / 256, 256, 0, stream>>>(deg, pool, N + 1, B * 256);

    k_cvt<<<(NX + 255) / 256, 256, 0, stream>>>(x_raw, xc, NX, flag);
    k_cvt<<<(NW1 + 255) / 256, 256, 0, stream>>>(d_in[3], w1c, NW1, flag);
    k_cvt<<<(NW2 + 255) / 256, 256, 0, stream>>>(d_in[13], w2c, NW2, flag);
    k_cvt_small<<<18, 256, 0, stream>>>(
        d_in[4], d_in[5], d_in[6], d_in[7], d_in[8], d_in[9], d_in[10], d_in[11], d_in[12],
        d_in[14], d_in[15], d_in[16], d_in[17], d_in[18], d_in[19], d_in[20], d_in[21], d_in[22],
        sc, flag);

    k_transpose<<<256, 256, 0, stream>>>(w1c, wt1);
    k_transpose<<<256, 256, 0, stream>>>(w2c, wt2);   // first 256 rows of W2
    k_root<<<1, 256, 0, stream>>>(batch, root, N, B);

    k_hist<<<(E + 255) / 256, 256, 0, stream>>>(ei, deg, E);
    int nb1 = (N + 1 + 2047) / 2048;
    k_scan1<<<nb1, 256, 0, stream>>>(deg, pscan, bsums, N + 1);
    k_scan2<<<1, 64, 0, stream>>>(bsums, nb1);
    k_scan3<<<(N + 1 + 255) / 256, 256, 0, stream>>>(pscan, bsums, ptr, cursor, N + 1, N);
    k_fill<<<(E + 255) / 256, 256, 0, stream>>>(ei, cursor, csr, E);

    int mt = (N + 127) / 128;
    int ngrid = (N + 3) / 4;
    // layer 1
    k_gemm<<<mt * 2, 256, 0, stream>>>(xc, wt1, hbuf, N, nullptr, nullptr);
    k_al<<<ngrid, 256, 0, stream>>>(hbuf, sc + 0 * 256, sc + 1 * 256, als, ald, N);
    k_attw<<<ngrid, 256, 0, stream>>>(als, ald, ptr, csr, aw, sfp, ivs, N);
    k_agg2<<<ngrid, 256, 0, stream>>>(hbuf, aw, sfp, ivs, ptr, csr,
        sc + 2 * 256, sc + 3 * 256, sc + 4 * 256, sc + 5 * 256, sc + 6 * 256, sc + 7 * 256, sc + 8 * 256,
        x2, nullptr, batch, N);
    // layer 2
    k_r2<<<B, 256, 0, stream>>>(xc, w2c, root, r2, N);
    k_gemm<<<mt * 2, 256, 0, stream>>>(x2, wt2, hbuf, N, r2, batch);
    k_al<<<ngrid, 256, 0, stream>>>(hbuf, sc + 9 * 256, sc + 10 * 256, als, ald, N);
    k_attw<<<ngrid, 256, 0, stream>>>(als, ald, ptr, csr, aw, sfp, ivs, N);
    k_agg2<<<ngrid, 256, 0, stream>>>(hbuf, aw, sfp, ivs, ptr, csr,
        sc + 11 * 256, sc + 12 * 256, sc + 13 * 256, sc + 14 * 256, sc + 15 * 256, sc + 16 * 256, sc + 17 * 256,
        nullptr, pool, batch, N);

    k_final<<<B, 256, 0, stream>>>(pool, x2, root, d_out, flag);
    (void)ws_size;
}